// Round 1
// baseline (568.100 us; speedup 1.0000x reference)
//
#include <hip/hip_runtime.h>

// VectorQuantizer: z (32,64,64,64) fp32, embedding_w (2048,64) fp32.
// Outputs concat: quantized_out (32,64,64,64) | indices (32,64,64) as float | loss (1)
//
// Numerics: bit-exact replication of the numpy fp32 reference:
//   S_n = pairwise64(z_n^2), b_k = pairwise64(w_k^2)  (numpy pairwise_sum order)
//   C_nk = sequential fp32 FMA chain over c=0..63 (BLAS sgemm k-order)
//   d = fp32(fp32(S + b) - fp32(2*C)), argmin first-index tie-break.
// All separately-rounded steps use __fadd_rn/__fmul_rn/__fsub_rn so that
// -ffp-contract=fast cannot fuse them; the dot chain uses explicit fmaf.

#define NROWS   131072
#define KCODES  2048
#define CDIM    64
#define ZSTRIDE 68          // LDS pad: row stride 68 floats (16B-aligned, 2-way max conflicts)
#define OUT_Q   0
#define OUT_IDX 8388608
#define OUT_LOSS 8519680

__device__ __forceinline__ float pairwise64(const float a[64]) {
    // numpy pairwise_sum, n=64 path: 8 accumulators stride 8, then fixed tree
    float r[8];
#pragma unroll
    for (int j = 0; j < 8; ++j) r[j] = a[j];
#pragma unroll
    for (int m = 1; m < 8; ++m)
#pragma unroll
        for (int j = 0; j < 8; ++j) r[j] = __fadd_rn(r[j], a[m * 8 + j]);
    float s01 = __fadd_rn(r[0], r[1]);
    float s23 = __fadd_rn(r[2], r[3]);
    float s45 = __fadd_rn(r[4], r[5]);
    float s67 = __fadd_rn(r[6], r[7]);
    float s0123 = __fadd_rn(s01, s23);
    float s4567 = __fadd_rn(s45, s67);
    return __fadd_rn(s0123, s4567);
}

__device__ __forceinline__ float fc(const float4& v, int i) {
    return i == 0 ? v.x : (i == 1 ? v.y : (i == 2 ? v.z : v.w));
}

// ---------------- kernel A: b_k = pairwise64(w_k^2) ----------------
__global__ __launch_bounds__(256) void vq_bsum(const float* __restrict__ w,
                                               float* __restrict__ bsum) {
    int k = blockIdx.x * 256 + threadIdx.x;   // grid = 8 blocks -> k < 2048
    const float4* wr = (const float4*)(w + (size_t)k * CDIM);
    float a[64];
#pragma unroll
    for (int m = 0; m < 16; ++m) {
        float4 v = wr[m];
        a[4 * m + 0] = __fmul_rn(v.x, v.x);
        a[4 * m + 1] = __fmul_rn(v.y, v.y);
        a[4 * m + 2] = __fmul_rn(v.z, v.z);
        a[4 * m + 3] = __fmul_rn(v.w, v.w);
    }
    bsum[k] = pairwise64(a);
}

// ---------------- kernel B: main VQ ----------------
// Block = one (b,h): 64 rows (w=0..63). 256 threads: cl = t&15 (code lane),
// rg = t>>4 (row group, 4 rows each). Register tile 4 rows x 8 codes.
__global__ __launch_bounds__(256, 3) void vq_main(const float* __restrict__ z,
                                                  const float* __restrict__ w,
                                                  const float* __restrict__ bsum,
                                                  float* __restrict__ out,
                                                  float* __restrict__ partial) {
    __shared__ float zt[64 * ZSTRIDE];
    __shared__ float wt[128 * ZSTRIDE];
    __shared__ float bt[128];
    __shared__ float Ss[64];
    __shared__ int   idxs[64];
    __shared__ double lred[4];

    const int t  = threadIdx.x;
    const int cl = t & 15;
    const int rg = t >> 4;
    const int bh = blockIdx.x;          // 0..2047
    const int b  = bh >> 6;
    const int h  = bh & 63;
    const size_t zbase = (size_t)b * 262144 + (size_t)h * 64;

    // ---- stage z tile (transpose to zt[w][c]) ----
#pragma unroll
    for (int m = 0; m < 4; ++m) {
        int i4 = t + 256 * m;           // 0..1023 float4s
        int c  = i4 >> 4;               // 0..63
        int w4 = i4 & 15;               // 0..15
        float4 v = *(const float4*)(z + zbase + (size_t)c * 4096 + 4 * w4);
        zt[(4 * w4 + 0) * ZSTRIDE + c] = v.x;
        zt[(4 * w4 + 1) * ZSTRIDE + c] = v.y;
        zt[(4 * w4 + 2) * ZSTRIDE + c] = v.z;
        zt[(4 * w4 + 3) * ZSTRIDE + c] = v.w;
    }
    __syncthreads();

    // ---- S per row: numpy pairwise of squares ----
    if (t < 64) {
        float a[64];
#pragma unroll
        for (int m = 0; m < 16; ++m) {
            float4 v = *(const float4*)&zt[t * ZSTRIDE + 4 * m];
            a[4 * m + 0] = __fmul_rn(v.x, v.x);
            a[4 * m + 1] = __fmul_rn(v.y, v.y);
            a[4 * m + 2] = __fmul_rn(v.z, v.z);
            a[4 * m + 3] = __fmul_rn(v.w, v.w);
        }
        Ss[t] = pairwise64(a);
    }
    __syncthreads();

    float sreg[4];
#pragma unroll
    for (int i = 0; i < 4; ++i) sreg[i] = Ss[4 * rg + i];

    float dmin[4];
    int   kmin[4];
#pragma unroll
    for (int i = 0; i < 4; ++i) { dmin[i] = __builtin_inff(); kmin[i] = 0; }

    // ---- K loop: 16 tiles of 128 codes ----
    for (int kt = 0; kt < 16; ++kt) {
        // stage w tile
#pragma unroll
        for (int m = 0; m < 8; ++m) {
            int i4 = t + 256 * m;       // 0..2047 float4s
            int kk = i4 >> 4;           // 0..127
            int c4 = i4 & 15;
            float4 v = *((const float4*)w + (size_t)(kt * 128 + kk) * 16 + c4);
            *(float4*)&wt[kk * ZSTRIDE + 4 * c4] = v;
        }
        if (t < 128) bt[t] = bsum[kt * 128 + t];
        __syncthreads();

        float acc[4][8];
#pragma unroll
        for (int i = 0; i < 4; ++i)
#pragma unroll
            for (int j = 0; j < 8; ++j) acc[i][j] = 0.f;

        for (int c0 = 0; c0 < 64; c0 += 4) {
            float4 zr[4], wr[8];
#pragma unroll
            for (int i = 0; i < 4; ++i)
                zr[i] = *(const float4*)&zt[(4 * rg + i) * ZSTRIDE + c0];
#pragma unroll
            for (int j = 0; j < 8; ++j)
                wr[j] = *(const float4*)&wt[(cl + 16 * j) * ZSTRIDE + c0];
#pragma unroll
            for (int cc = 0; cc < 4; ++cc)
#pragma unroll
                for (int i = 0; i < 4; ++i)
#pragma unroll
                    for (int j = 0; j < 8; ++j)
                        acc[i][j] = __builtin_fmaf(fc(zr[i], cc), fc(wr[j], cc), acc[i][j]);
        }

        // d = fp32((S + b) - 2*C), strict < keeps earliest k (k ascending in j, kt)
#pragma unroll
        for (int i = 0; i < 4; ++i) {
            float s = sreg[i];
#pragma unroll
            for (int j = 0; j < 8; ++j) {
                int   kl = cl + 16 * j;
                float d  = __fsub_rn(__fadd_rn(s, bt[kl]), __fmul_rn(2.f, acc[i][j]));
                int   kg = kt * 128 + kl;
                if (d < dmin[i]) { dmin[i] = d; kmin[i] = kg; }
            }
        }
        __syncthreads();
    }

    // ---- cross-lane argmin over the 16 code lanes (tie -> smaller index) ----
#pragma unroll
    for (int i = 0; i < 4; ++i) {
        float d  = dmin[i];
        int   kg = kmin[i];
#pragma unroll
        for (int off = 1; off < 16; off <<= 1) {
            float od = __shfl_xor(d, off, 64);
            int   ok = __shfl_xor(kg, off, 64);
            if (od < d || (od == d && ok < kg)) { d = od; kg = ok; }
        }
        if (cl == 0) idxs[4 * rg + i] = kg;
    }
    __syncthreads();

    // ---- epilogue: quantized output (replicated STE rounding) + loss ----
    double lacc = 0.0;
#pragma unroll
    for (int m = 0; m < 16; ++m) {
        int i  = t + 256 * m;           // 0..4095
        int c  = i >> 6;
        int ww = i & 63;
        int kq = idxs[ww];
        float q  = w[(size_t)kq * CDIM + c];
        float zv = zt[ww * ZSTRIDE + c];
        float t1  = __fsub_rn(q, zv);          // quantized - zp
        float val = __fadd_rn(zv, t1);         // zp + (q - zp)
        out[OUT_Q + zbase + (size_t)c * 4096 + ww] = val;
        float sq = __fmul_rn(t1, t1);
        lacc += (double)sq;
    }
    if (t < 64) {
        out[OUT_IDX + (size_t)b * 4096 + (size_t)h * 64 + t] = (float)idxs[t];
    }

    // block-reduce loss partial
#pragma unroll
    for (int off = 1; off < 64; off <<= 1) lacc += __shfl_xor(lacc, off, 64);
    if ((t & 63) == 0) lred[t >> 6] = lacc;
    __syncthreads();
    if (t == 0) {
        double tot = lred[0] + lred[1] + lred[2] + lred[3];
        partial[bh] = (float)(tot * (0.25 / 8388608.0));
    }
}

// ---------------- kernel C: reduce loss partials ----------------
__global__ __launch_bounds__(256) void vq_loss(const float* __restrict__ partial,
                                               float* __restrict__ out) {
    int t = threadIdx.x;
    double s = 0.0;
#pragma unroll
    for (int m = 0; m < 8; ++m) s += (double)partial[t + 256 * m];
#pragma unroll
    for (int off = 1; off < 64; off <<= 1) s += __shfl_xor(s, off, 64);
    __shared__ double sr[4];
    if ((t & 63) == 0) sr[t >> 6] = s;
    __syncthreads();
    if (t == 0) out[OUT_LOSS] = (float)(sr[0] + sr[1] + sr[2] + sr[3]);
}

extern "C" void kernel_launch(void* const* d_in, const int* in_sizes, int n_in,
                              void* d_out, int out_size, void* d_ws, size_t ws_size,
                              hipStream_t stream) {
    (void)in_sizes; (void)n_in; (void)out_size; (void)ws_size;
    const float* z = (const float*)d_in[0];
    const float* w = (const float*)d_in[1];
    float* out     = (float*)d_out;
    float* bsum    = (float*)d_ws;          // 2048 floats
    float* partial = bsum + KCODES;         // 2048 floats

    vq_bsum<<<8, 256, 0, stream>>>(w, bsum);
    vq_main<<<2048, 256, 0, stream>>>(z, w, bsum, out, partial);
    vq_loss<<<1, 256, 0, stream>>>(partial, out);
}

// Round 2
// 513.351 us; speedup vs baseline: 1.1066x; 1.1066x over previous
//
#include <hip/hip_runtime.h>

// VectorQuantizer: z (32,64,64,64) fp32, embedding_w (2048,64) fp32.
// Outputs concat: quantized_out (32,64,64,64) | indices (32,64,64) as float | loss (1)
//
// Numerics: bit-exact replication of the numpy fp32 reference (verified R1, absmax 0):
//   S_n = pairwise64(z_n^2), b_k = pairwise64(w_k^2)  (numpy pairwise_sum order)
//   C_nk = sequential fp32 FMA chain over c=0..63 ascending
//   d = fp32(fp32(S + b) - fp32(2*C)), argmin first-index tie-break.
// All separately-rounded steps use __fadd_rn/__fmul_rn/__fsub_rn so that
// -ffp-contract=fast cannot fuse them; the dot chain uses explicit fmaf.
//
// R2: 8x8 register tile (was 4x8) to halve ds_read per FMA (LDS-feed bound).
// Block = 128 rows (2 h-values); rows assigned stride-16 per thread so the 4
// row-groups of a wave hit distinct LDS banks (68-float stride = 4 banks apart).

#define KCODES  2048
#define CDIM    64
#define ZS      68          // LDS row stride in floats (16B-aligned, conflict-benign)
#define OUT_Q   0
#define OUT_IDX 8388608
#define OUT_LOSS 8519680

__device__ __forceinline__ float pairwise64(const float a[64]) {
    // numpy pairwise_sum, n=64 path: 8 accumulators stride 8, then fixed tree
    float r[8];
#pragma unroll
    for (int j = 0; j < 8; ++j) r[j] = a[j];
#pragma unroll
    for (int m = 1; m < 8; ++m)
#pragma unroll
        for (int j = 0; j < 8; ++j) r[j] = __fadd_rn(r[j], a[m * 8 + j]);
    float s01 = __fadd_rn(r[0], r[1]);
    float s23 = __fadd_rn(r[2], r[3]);
    float s45 = __fadd_rn(r[4], r[5]);
    float s67 = __fadd_rn(r[6], r[7]);
    float s0123 = __fadd_rn(s01, s23);
    float s4567 = __fadd_rn(s45, s67);
    return __fadd_rn(s0123, s4567);
}

__device__ __forceinline__ float fc(const float4& v, int i) {
    return i == 0 ? v.x : (i == 1 ? v.y : (i == 2 ? v.z : v.w));
}

// ---------------- kernel A: b_k = pairwise64(w_k^2) ----------------
__global__ __launch_bounds__(256) void vq_bsum(const float* __restrict__ w,
                                               float* __restrict__ bsum) {
    int k = blockIdx.x * 256 + threadIdx.x;   // grid = 8 blocks -> k < 2048
    const float4* wr = (const float4*)(w + (size_t)k * CDIM);
    float a[64];
#pragma unroll
    for (int m = 0; m < 16; ++m) {
        float4 v = wr[m];
        a[4 * m + 0] = __fmul_rn(v.x, v.x);
        a[4 * m + 1] = __fmul_rn(v.y, v.y);
        a[4 * m + 2] = __fmul_rn(v.z, v.z);
        a[4 * m + 3] = __fmul_rn(v.w, v.w);
    }
    bsum[k] = pairwise64(a);
}

// ---------------- kernel B: main VQ ----------------
// Block = 2 h-values: 128 rows. 256 threads: cl = t&15 (code lane),
// rg = t>>4 (row group). Each thread: rows {rg+16i}, codes {cl+16j} per tile.
// Register tile 8 rows x 8 codes.
__global__ __launch_bounds__(256, 2) void vq_main(const float* __restrict__ z,
                                                  const float* __restrict__ w,
                                                  const float* __restrict__ bsum,
                                                  float* __restrict__ out,
                                                  float* __restrict__ partial) {
    __shared__ float zt[128 * ZS];
    __shared__ float wt[128 * ZS];
    __shared__ float bt[128];
    __shared__ float Ss[128];
    __shared__ int   idxs[128];
    __shared__ double lred[4];

    const int t  = threadIdx.x;
    const int cl = t & 15;
    const int rg = t >> 4;
    const int blk = blockIdx.x;          // 0..1023
    const int b   = blk >> 5;
    const int hp  = blk & 31;            // h = 2*hp
    const size_t zbase = (size_t)b * 262144 + (size_t)hp * 128;

    // ---- stage z tile (transpose to zt[r][c], r = hsel*64 + w) ----
#pragma unroll
    for (int m = 0; m < 8; ++m) {
        int i4   = t + 256 * m;          // 0..2047 float4s
        int c    = i4 >> 5;              // 0..63
        int rem  = i4 & 31;
        int hsel = rem >> 4;
        int w4   = rem & 15;
        float4 v = *(const float4*)(z + zbase + (size_t)c * 4096 + hsel * 64 + 4 * w4);
        int r0 = hsel * 64 + 4 * w4;
        zt[(r0 + 0) * ZS + c] = v.x;
        zt[(r0 + 1) * ZS + c] = v.y;
        zt[(r0 + 2) * ZS + c] = v.z;
        zt[(r0 + 3) * ZS + c] = v.w;
    }
    __syncthreads();

    // ---- S per row: numpy pairwise of squares ----
    if (t < 128) {
        float a[64];
#pragma unroll
        for (int m = 0; m < 16; ++m) {
            float4 v = *(const float4*)&zt[t * ZS + 4 * m];
            a[4 * m + 0] = __fmul_rn(v.x, v.x);
            a[4 * m + 1] = __fmul_rn(v.y, v.y);
            a[4 * m + 2] = __fmul_rn(v.z, v.z);
            a[4 * m + 3] = __fmul_rn(v.w, v.w);
        }
        Ss[t] = pairwise64(a);
    }
    __syncthreads();

    float sreg[8];
#pragma unroll
    for (int i = 0; i < 8; ++i) sreg[i] = Ss[rg + 16 * i];

    float dmin[8];
    int   kmin[8];
#pragma unroll
    for (int i = 0; i < 8; ++i) { dmin[i] = __builtin_inff(); kmin[i] = 0; }

    // ---- K loop: 16 tiles of 128 codes ----
    for (int kt = 0; kt < 16; ++kt) {
        // stage w tile
#pragma unroll
        for (int m = 0; m < 8; ++m) {
            int i4 = t + 256 * m;        // 0..2047 float4s
            int kk = i4 >> 4;            // 0..127
            int c4 = i4 & 15;
            float4 v = *((const float4*)w + (size_t)(kt * 128 + kk) * 16 + c4);
            *(float4*)&wt[kk * ZS + 4 * c4] = v;
        }
        if (t < 128) bt[t] = bsum[kt * 128 + t];
        __syncthreads();

        float acc[8][8];
#pragma unroll
        for (int i = 0; i < 8; ++i)
#pragma unroll
            for (int j = 0; j < 8; ++j) acc[i][j] = 0.f;

        for (int c0 = 0; c0 < 64; c0 += 4) {
            float4 zr[8], wr[8];
#pragma unroll
            for (int i = 0; i < 8; ++i)
                zr[i] = *(const float4*)&zt[(rg + 16 * i) * ZS + c0];
#pragma unroll
            for (int j = 0; j < 8; ++j)
                wr[j] = *(const float4*)&wt[(cl + 16 * j) * ZS + c0];
#pragma unroll
            for (int cc = 0; cc < 4; ++cc)
#pragma unroll
                for (int i = 0; i < 8; ++i)
#pragma unroll
                    for (int j = 0; j < 8; ++j)
                        acc[i][j] = __builtin_fmaf(fc(zr[i], cc), fc(wr[j], cc), acc[i][j]);
        }

        // d = fp32((S + b) - 2*C), strict < keeps earliest k (k ascending in j, kt)
#pragma unroll
        for (int i = 0; i < 8; ++i) {
            float s = sreg[i];
#pragma unroll
            for (int j = 0; j < 8; ++j) {
                int   kl = cl + 16 * j;
                float d  = __fsub_rn(__fadd_rn(s, bt[kl]), __fmul_rn(2.f, acc[i][j]));
                int   kg = kt * 128 + kl;
                if (d < dmin[i]) { dmin[i] = d; kmin[i] = kg; }
            }
        }
        __syncthreads();
    }

    // ---- cross-lane argmin over the 16 code lanes (tie -> smaller index) ----
#pragma unroll
    for (int i = 0; i < 8; ++i) {
        float d  = dmin[i];
        int   kg = kmin[i];
#pragma unroll
        for (int off = 1; off < 16; off <<= 1) {
            float od = __shfl_xor(d, off, 64);
            int   ok = __shfl_xor(kg, off, 64);
            if (od < d || (od == d && ok < kg)) { d = od; kg = ok; }
        }
        if (cl == 0) idxs[rg + 16 * i] = kg;
    }
    __syncthreads();

    // ---- epilogue: quantized output (replicated STE rounding) + loss ----
    double lacc = 0.0;
#pragma unroll
    for (int m = 0; m < 32; ++m) {
        int i = t + 256 * m;             // 0..8191
        int c = i >> 7;                  // 0..63
        int r = i & 127;
        int hsel = r >> 6;
        int ww = r & 63;
        int kq = idxs[r];
        float q  = w[(size_t)kq * CDIM + c];
        float zv = zt[r * ZS + c];
        float t1  = __fsub_rn(q, zv);          // quantized - zp
        float val = __fadd_rn(zv, t1);         // zp + (q - zp)
        out[OUT_Q + zbase + (size_t)c * 4096 + hsel * 64 + ww] = val;
        lacc += (double)__fmul_rn(t1, t1);
    }
    if (t < 128) {
        out[OUT_IDX + (size_t)b * 4096 + (size_t)hp * 128 + t] = (float)idxs[t];
    }

    // block-reduce loss partial
#pragma unroll
    for (int off = 1; off < 64; off <<= 1) lacc += __shfl_xor(lacc, off, 64);
    if ((t & 63) == 0) lred[t >> 6] = lacc;
    __syncthreads();
    if (t == 0) {
        double tot = lred[0] + lred[1] + lred[2] + lred[3];
        partial[blk] = (float)(tot * (0.25 / 8388608.0));
    }
}

// ---------------- kernel C: reduce loss partials (1024) ----------------
__global__ __launch_bounds__(256) void vq_loss(const float* __restrict__ partial,
                                               float* __restrict__ out) {
    int t = threadIdx.x;
    double s = 0.0;
#pragma unroll
    for (int m = 0; m < 4; ++m) s += (double)partial[t + 256 * m];
#pragma unroll
    for (int off = 1; off < 64; off <<= 1) s += __shfl_xor(s, off, 64);
    __shared__ double sr[4];
    if ((t & 63) == 0) sr[t >> 6] = s;
    __syncthreads();
    if (t == 0) out[OUT_LOSS] = (float)(sr[0] + sr[1] + sr[2] + sr[3]);
}

extern "C" void kernel_launch(void* const* d_in, const int* in_sizes, int n_in,
                              void* d_out, int out_size, void* d_ws, size_t ws_size,
                              hipStream_t stream) {
    (void)in_sizes; (void)n_in; (void)out_size; (void)ws_size;
    const float* z = (const float*)d_in[0];
    const float* w = (const float*)d_in[1];
    float* out     = (float*)d_out;
    float* bsum    = (float*)d_ws;          // 2048 floats
    float* partial = bsum + KCODES;         // 1024 floats

    vq_bsum<<<8, 256, 0, stream>>>(w, bsum);
    vq_main<<<1024, 256, 0, stream>>>(z, w, bsum, out, partial);
    vq_loss<<<1, 256, 0, stream>>>(partial, out);
}